// Round 1
// baseline (23680.762 us; speedup 1.0000x reference)
//
#include <hip/hip_runtime.h>

// LSTM B=64 T=512 IN=512 H=1024 OUT=512, all fp32 in/out.
// Strategy: persistent-RNN. 256 WGs (2 groups x 128), W held in VGPRs as fp16
// MFMA fragments, one 128-WG flag barrier per timestep, h double-buffered in ws.

#define B_   64
#define T_   512
#define IN_  512
#define H_   1024
#define G4_  4096   // 4*H
#define OUT_ 512

typedef _Float16 f16;
typedef _Float16 f16x8 __attribute__((ext_vector_type(8)));
typedef _Float16 f16x4 __attribute__((ext_vector_type(4)));
typedef float f32x4  __attribute__((ext_vector_type(4)));
typedef float f32x16 __attribute__((ext_vector_type(16)));

// workspace layout (bytes)
#define X16_OFF   0UL                         // [64][512][512] f16 = 33554432
#define WOT_OFF   33554432UL                  // W_out^T [512][1024] f16 = 1048576
#define H_OFF     (WOT_OFF + 1048576UL)       // h: [2 grp][2 buf][32][1024] f16 = 262144
#define FLG_OFF   (H_OFF + 262144UL)          // flags: 2 * 256 u32 = 2048
#define WS_NEED   (FLG_OFF + 2048UL)
#define ZERO_BYTES (262144UL + 2048UL)        // h + flags zeroed together

__device__ __forceinline__ float sigmoidf_(float v) { return 1.f / (1.f + __expf(-v)); }
__device__ __forceinline__ float tanhf_(float v) { return 1.f - 2.f / (__expf(2.f * v) + 1.f); }

__global__ __launch_bounds__(256) void lstm_prepass(
    const float* __restrict__ x, const float* __restrict__ Wout,
    f16* __restrict__ x16, f16* __restrict__ WoT) {
  long i = (long)blockIdx.x * blockDim.x + threadIdx.x;
  long stride = (long)gridDim.x * blockDim.x;
  const long n4 = (long)B_ * T_ * IN_ / 4;
  const float4* x4 = (const float4*)x;
  f16x4* o4 = (f16x4*)x16;
  for (long p = i; p < n4; p += stride) {
    float4 v = x4[p];
    f16x4 o = { (f16)v.x, (f16)v.y, (f16)v.z, (f16)v.w };
    o4[p] = o;
  }
  const long nw = (long)H_ * OUT_;
  for (long p = i; p < nw; p += stride) {
    long k = p / OUT_, c = p % OUT_;
    WoT[c * (long)H_ + k] = (f16)Wout[p];
  }
}

// 256 WGs x 256 threads. WG wg: group g = wg>>7 (batch rows g*32..g*32+31),
// wgi = wg&127 owns h-cols [wgi*8, wgi*8+8) i.e. gate cols {gt*1024 + wgi*8 + j}.
// 4 waves K-split over K=1536 (x: 128/wave, h: 256/wave).
__global__ __launch_bounds__(256, 2) void lstm_main(
    const float* __restrict__ W, const float* __restrict__ b,
    const f16* __restrict__ x16, f16* hbuf, unsigned int* flags) {

  const int wg   = blockIdx.x;
  const int g    = wg >> 7;
  const int wgi  = wg & 127;
  const int tid  = threadIdx.x;
  const int wave = tid >> 6;
  const int lane = tid & 63;

  const int hbase   = wgi * 8;
  const int colLane = lane & 31;        // MFMA N index (local col)
  const int khalf   = (lane >> 5) * 8;  // MFMA K sub-index
  const int arow    = lane & 31;        // MFMA M index (batch row in group)

  // ---- persistent W fragments in VGPRs (fp32 -> fp16, MFMA B layout) ----
  // local col c: gate gt = c>>3, hcol = hbase + (c&7) -> global col gt*1024+hbase+(c&7)
  f16x8 wf[24];
  {
    const int gcol = (colLane >> 3) * H_ + hbase + (colLane & 7);
    #pragma unroll
    for (int f = 0; f < 24; ++f) {
      const int k0 = (f < 8) ? (128 * wave + 16 * f)
                             : (512 + 256 * wave + 16 * (f - 8));
      f16x8 v;
      #pragma unroll
      for (int j = 0; j < 8; ++j)
        v[j] = (f16)W[(long)(k0 + khalf + j) * G4_ + gcol];
      wf[f] = v;
    }
  }

  // epilogue ownership: thread -> (row erow, hcol offset ej)
  const int erow = tid >> 3;
  const int ej   = tid & 7;
  float bias[4];
  #pragma unroll
  for (int gt = 0; gt < 4; ++gt) bias[gt] = b[gt * H_ + hbase + ej];

  float c_state = 0.f;

  __shared__ float red[4][32][36];  // [wave][row][col], padded vs bank conflicts

  const f16* xg   = x16 + (long)(g * 32) * T_ * IN_;
  f16* hb         = hbuf + (long)g * 2 * 32 * H_;   // [2][32][1024]
  unsigned int* flg = flags + g * 256;              // 128 used

  for (int t = 0; t < T_; ++t) {
    f32x16 acc = {};

    // ---- x-part: independent of h_t, issued before the barrier wait ----
    {
      const f16* xrow = xg + (long)arow * (T_ * IN_) + (long)t * IN_
                           + 128 * wave + khalf;
      f16x8 xa[8];
      #pragma unroll
      for (int f = 0; f < 8; ++f)
        xa[f] = *(const f16x8*)(xrow + 16 * f);
      #pragma unroll
      for (int f = 0; f < 8; ++f)
        acc = __builtin_amdgcn_mfma_f32_32x32x16_f16(xa[f], wf[f], acc, 0, 0, 0);
    }

    // ---- wait until all 128 WGs of this group published h_t ----
    if (t > 0) {
      if (wave == 0) {
        const unsigned int tgt = (unsigned int)t;
        int ok;
        long guard = 0;
        do {
          unsigned int f0 = __hip_atomic_load(&flg[2 * lane],     __ATOMIC_RELAXED, __HIP_MEMORY_SCOPE_AGENT);
          unsigned int f1 = __hip_atomic_load(&flg[2 * lane + 1], __ATOMIC_RELAXED, __HIP_MEMORY_SCOPE_AGENT);
          ok = (f0 >= tgt) && (f1 >= tgt);
        } while (!__all(ok) && ++guard < (1L << 24));
      }
      __syncthreads();
      __threadfence();   // acquire: invalidate stale h lines (cross-XCD)
    }

    // ---- h-part ----
    {
      const f16* hrow = hb + (long)(t & 1) * (32 * H_) + (long)arow * H_
                           + 256 * wave + khalf;
      f16x8 ha[16];
      #pragma unroll
      for (int f = 0; f < 16; ++f)
        ha[f] = *(const f16x8*)(hrow + 16 * f);
      #pragma unroll
      for (int f = 0; f < 16; ++f)
        acc = __builtin_amdgcn_mfma_f32_32x32x16_f16(ha[f], wf[8 + f], acc, 0, 0, 0);
    }

    // ---- cross-wave K-reduction via LDS ----
    // C layout (32x32): col = lane&31, row = (reg&3) + 8*(reg>>2) + 4*(lane>>5)
    #pragma unroll
    for (int r = 0; r < 16; ++r) {
      const int row = (r & 3) + 8 * (r >> 2) + 4 * (lane >> 5);
      red[wave][row][colLane] = acc[r];
    }
    __syncthreads();

    // ---- epilogue: gates, c/h update ----
    float f4[4];
    #pragma unroll
    for (int gt = 0; gt < 4; ++gt) {
      float s = bias[gt];
      #pragma unroll
      for (int w = 0; w < 4; ++w) s += red[w][erow][gt * 8 + ej];
      f4[gt] = s;
    }
    const float fg = sigmoidf_(f4[0]);
    const float ig = sigmoidf_(f4[1]);
    const float gg = tanhf_(f4[2]);
    const float og = sigmoidf_(f4[3]);
    c_state = c_state * fg + ig * gg;
    const float hv = og * tanhf_(c_state);
    hb[(long)((t + 1) & 1) * (32 * H_) + (long)erow * H_ + hbase + ej] = (f16)hv;

    __threadfence();      // release: make h writes visible device-wide
    __syncthreads();      // all threads' fences done before flag store
    if (tid == 0)
      __hip_atomic_store(&flg[wgi], (unsigned int)(t + 1),
                         __ATOMIC_RELEASE, __HIP_MEMORY_SCOPE_AGENT);
  }
}

// out = h_T @ W_out + b_out : [64,1024]@[1024,512]. h_T is in h buf 0 (T even).
// 128 WGs: 4 row-tiles x 32 col-tiles of 16x16; 4 waves K-split 256 each.
__global__ __launch_bounds__(256) void lstm_out(
    const f16* __restrict__ hbuf, const f16* __restrict__ WoT,
    const float* __restrict__ bout, float* __restrict__ out) {
  const int wgid = blockIdx.x;
  const int rowT = wgid >> 5;   // 0..3
  const int colT = wgid & 31;   // 0..31
  const int tid  = threadIdx.x;
  const int wave = tid >> 6;
  const int lane = tid & 63;
  const int r16  = lane & 15;
  const int ksel = (lane >> 4) * 8;

  const int g = rowT >> 1;
  const f16* hrow = hbuf + (long)g * 2 * 32 * H_            // group base (buf 0)
                  + (long)((rowT & 1) * 16 + r16) * H_;
  const f16* wrow = WoT + (long)(colT * 16 + r16) * H_;

  f32x4 acc = {};
  #pragma unroll
  for (int f = 0; f < 8; ++f) {
    f16x8 a  = *(const f16x8*)(hrow + 256 * wave + 32 * f + ksel);
    f16x8 bf = *(const f16x8*)(wrow + 256 * wave + 32 * f + ksel);
    acc = __builtin_amdgcn_mfma_f32_16x16x32_f16(a, bf, acc, 0, 0, 0);
  }

  __shared__ float red[4][16][20];
  #pragma unroll
  for (int r = 0; r < 4; ++r)
    red[wave][(lane >> 4) * 4 + r][lane & 15] = acc[r];
  __syncthreads();

  const int row = tid >> 4;   // 0..15
  const int col = tid & 15;
  float s = bout[colT * 16 + col];
  #pragma unroll
  for (int w = 0; w < 4; ++w) s += red[w][row][col];
  out[(long)(rowT * 16 + row) * OUT_ + colT * 16 + col] = s;
}

extern "C" void kernel_launch(void* const* d_in, const int* in_sizes, int n_in,
                              void* d_out, int out_size, void* d_ws, size_t ws_size,
                              hipStream_t stream) {
  const float* x    = (const float*)d_in[0];
  const float* W    = (const float*)d_in[1];
  const float* b    = (const float*)d_in[2];
  const float* Wout = (const float*)d_in[3];
  const float* bout = (const float*)d_in[4];
  float* out = (float*)d_out;

  if (ws_size < WS_NEED) return;  // avoid corrupting memory if ws too small

  char* wsb = (char*)d_ws;
  f16* x16  = (f16*)(wsb + X16_OFF);
  f16* WoT  = (f16*)(wsb + WOT_OFF);
  f16* hbuf = (f16*)(wsb + H_OFF);
  unsigned int* flags = (unsigned int*)(wsb + FLG_OFF);

  // zero h double-buffers (h0 = 0) and barrier flags
  hipMemsetAsync(wsb + H_OFF, 0, ZERO_BYTES, stream);

  lstm_prepass<<<1024, 256, 0, stream>>>(x, Wout, x16, WoT);

  // 256 WGs, >=2 fit per CU (256 VGPR cap, ~18KB LDS) -> all co-resident.
  lstm_main<<<256, 256, 0, stream>>>(W, b, x16, hbuf, flags);

  lstm_out<<<128, 256, 0, stream>>>(hbuf, WoT, bout, out);
}

// Round 2
// 2489.990 us; speedup vs baseline: 9.5104x; 9.5104x over previous
//
#include <hip/hip_runtime.h>

// LSTM B=64 T=512 IN=512 H=1024 OUT=512, all fp32 in/out.
// Persistent-RNN: 256 WGs (2 groups x 128), W held in VGPRs/AGPRs as fp16 MFMA
// fragments, one 128-WG flag barrier per timestep, h double-buffered in ws.
// R1 change: replaced per-step __threadfence (whole-L2 wbl2/inv on gfx950) with
// fine-grained agent-coherent accesses (sc0 sc1) on h + flags. No cache-wide
// maintenance anywhere in the main loop.

#define B_   64
#define T_   512
#define IN_  512
#define H_   1024
#define G4_  4096   // 4*H
#define OUT_ 512

typedef _Float16 f16;
typedef _Float16 f16x8 __attribute__((ext_vector_type(8)));
typedef _Float16 f16x4 __attribute__((ext_vector_type(4)));
typedef float f32x4  __attribute__((ext_vector_type(4)));
typedef float f32x16 __attribute__((ext_vector_type(16)));

// workspace layout (bytes)
#define X16_OFF   0UL                         // [64][512][512] f16 = 33554432
#define WOT_OFF   33554432UL                  // W_out^T [512][1024] f16 = 1048576
#define H_OFF     (WOT_OFF + 1048576UL)       // h: [2 grp][2 buf][32][1024] f16 = 262144
#define FLG_OFF   (H_OFF + 262144UL)          // flags: 2 * 256 u32 = 2048
#define WS_NEED   (FLG_OFF + 2048UL)
#define ZERO_BYTES (262144UL + 2048UL)        // h + flags zeroed together

__device__ __forceinline__ float sigmoidf_(float v) { return 1.f / (1.f + __expf(-v)); }
__device__ __forceinline__ float tanhf_(float v) { return 1.f - 2.f / (__expf(2.f * v) + 1.f); }

// Agent-coherent 16B load: bypasses L1 (sc0) and the non-coherent per-XCD L2
// (sc1); served by the coherent Infinity-Cache point. No buffer_inv needed.
__device__ __forceinline__ f16x8 ld_agent_b128(const f16* p) {
  f16x8 r;
  asm volatile("global_load_dwordx4 %0, %1, off sc0 sc1" : "=v"(r) : "v"(p));
  return r;
}

// Agent-coherent 2B store: write-through to the coherence point.
__device__ __forceinline__ void st_agent_b16(f16* p, f16 v) {
  unsigned int u = (unsigned int)__builtin_bit_cast(unsigned short, v);
  asm volatile("global_store_short %0, %1, off sc0 sc1" :: "v"(p), "v"(u) : "memory");
}

// Wait all outstanding VMEM, and fence the scheduler so register-only MFMAs
// can't be hoisted above the wait (rule #18 hazard class).
__device__ __forceinline__ void wait_vm0() {
  asm volatile("s_waitcnt vmcnt(0)" ::: "memory");
  __builtin_amdgcn_sched_barrier(0);
}

__global__ __launch_bounds__(256) void lstm_prepass(
    const float* __restrict__ x, const float* __restrict__ Wout,
    f16* __restrict__ x16, f16* __restrict__ WoT) {
  long i = (long)blockIdx.x * blockDim.x + threadIdx.x;
  long stride = (long)gridDim.x * blockDim.x;
  const long n4 = (long)B_ * T_ * IN_ / 4;
  const float4* x4 = (const float4*)x;
  f16x4* o4 = (f16x4*)x16;
  for (long p = i; p < n4; p += stride) {
    float4 v = x4[p];
    f16x4 o = { (f16)v.x, (f16)v.y, (f16)v.z, (f16)v.w };
    o4[p] = o;
  }
  const long nw = (long)H_ * OUT_;
  for (long p = i; p < nw; p += stride) {
    long k = p / OUT_, c = p % OUT_;
    WoT[c * (long)H_ + k] = (f16)Wout[p];
  }
}

// 256 WGs x 256 threads. WG wg: group g = wg>>7 (batch rows g*32..g*32+31),
// wgi = wg&127 owns h-cols [wgi*8, wgi*8+8) i.e. gate cols {gt*1024 + wgi*8 + j}.
// 4 waves K-split over K=1536 (x: 128/wave, h: 256/wave).
__global__ __launch_bounds__(256, 2) void lstm_main(
    const float* __restrict__ W, const float* __restrict__ b,
    const f16* __restrict__ x16, f16* hbuf, unsigned int* flags) {

  const int wg   = blockIdx.x;
  const int g    = wg >> 7;
  const int wgi  = wg & 127;
  const int tid  = threadIdx.x;
  const int wave = tid >> 6;
  const int lane = tid & 63;

  const int hbase   = wgi * 8;
  const int colLane = lane & 31;        // MFMA N index (local col)
  const int khalf   = (lane >> 5) * 8;  // MFMA K sub-index
  const int arow    = lane & 31;        // MFMA M index (batch row in group)

  // ---- persistent W fragments (fp32 -> fp16, MFMA B layout) ----
  f16x8 wf[24];
  {
    const int gcol = (colLane >> 3) * H_ + hbase + (colLane & 7);
    #pragma unroll
    for (int f = 0; f < 24; ++f) {
      const int k0 = (f < 8) ? (128 * wave + 16 * f)
                             : (512 + 256 * wave + 16 * (f - 8));
      f16x8 v;
      #pragma unroll
      for (int j = 0; j < 8; ++j)
        v[j] = (f16)W[(long)(k0 + khalf + j) * G4_ + gcol];
      wf[f] = v;
    }
  }

  // epilogue ownership: thread -> (row erow, hcol offset ej)
  const int erow = tid >> 3;
  const int ej   = tid & 7;
  float bias[4];
  #pragma unroll
  for (int gt = 0; gt < 4; ++gt) bias[gt] = b[gt * H_ + hbase + ej];

  float c_state = 0.f;

  __shared__ float red[4][32][36];  // [wave][row][col], padded vs bank conflicts

  const f16* xg   = x16 + (long)(g * 32) * T_ * IN_;
  f16* hb         = hbuf + (long)g * 2 * 32 * H_;   // [2][32][1024]
  unsigned int* flg = flags + g * 256;              // 128 used

  for (int t = 0; t < T_; ++t) {
    f32x16 acc = {};

    // ---- x-part: independent of h_t, issued before the barrier wait ----
    {
      const f16* xrow = xg + (long)arow * (T_ * IN_) + (long)t * IN_
                           + 128 * wave + khalf;
      f16x8 xa[8];
      #pragma unroll
      for (int f = 0; f < 8; ++f)
        xa[f] = *(const f16x8*)(xrow + 16 * f);
      #pragma unroll
      for (int f = 0; f < 8; ++f)
        acc = __builtin_amdgcn_mfma_f32_32x32x16_f16(xa[f], wf[f], acc, 0, 0, 0);
    }

    // ---- wait until all 128 WGs of this group published h_t ----
    if (t > 0) {
      if (wave == 0) {
        const unsigned int tgt = (unsigned int)t;
        int ok;
        long guard = 0;
        do {
          unsigned int f0 = __hip_atomic_load(&flg[2 * lane],     __ATOMIC_RELAXED, __HIP_MEMORY_SCOPE_AGENT);
          unsigned int f1 = __hip_atomic_load(&flg[2 * lane + 1], __ATOMIC_RELAXED, __HIP_MEMORY_SCOPE_AGENT);
          ok = (f0 >= tgt) && (f1 >= tgt);
        } while (!__all(ok) && ++guard < (1L << 24));
      }
      __syncthreads();   // ordering point; h loads below are L2-bypassing
    }

    // ---- h-part (agent-coherent loads; h published via sc1 stores) ----
    {
      const f16* hrow = hb + (long)(t & 1) * (32 * H_) + (long)arow * H_
                           + 256 * wave + khalf;
      f16x8 ha[16];
      #pragma unroll
      for (int f = 0; f < 16; ++f)
        ha[f] = ld_agent_b128(hrow + 16 * f);
      wait_vm0();
      #pragma unroll
      for (int f = 0; f < 16; ++f)
        acc = __builtin_amdgcn_mfma_f32_32x32x16_f16(ha[f], wf[8 + f], acc, 0, 0, 0);
    }

    // ---- cross-wave K-reduction via LDS ----
    // C layout (32x32): col = lane&31, row = (reg&3) + 8*(reg>>2) + 4*(lane>>5)
    #pragma unroll
    for (int r = 0; r < 16; ++r) {
      const int row = (r & 3) + 8 * (r >> 2) + 4 * (lane >> 5);
      red[wave][row][colLane] = acc[r];
    }
    __syncthreads();

    // ---- epilogue: gates, c/h update ----
    float f4[4];
    #pragma unroll
    for (int gt = 0; gt < 4; ++gt) {
      float s = bias[gt];
      #pragma unroll
      for (int w = 0; w < 4; ++w) s += red[w][erow][gt * 8 + ej];
      f4[gt] = s;
    }
    const float fg = sigmoidf_(f4[0]);
    const float ig = sigmoidf_(f4[1]);
    const float gg = tanhf_(f4[2]);
    const float og = sigmoidf_(f4[3]);
    c_state = c_state * fg + ig * gg;
    const float hv = og * tanhf_(c_state);
    st_agent_b16(&hb[(long)((t + 1) & 1) * (32 * H_) + (long)erow * H_ + hbase + ej],
                 (f16)hv);

    // ---- release: own sc1 stores acked at coherence point, then flag ----
    wait_vm0();
    __syncthreads();
    if (tid == 0)
      __hip_atomic_store(&flg[wgi], (unsigned int)(t + 1),
                         __ATOMIC_RELAXED, __HIP_MEMORY_SCOPE_AGENT);
  }
}

// out = h_T @ W_out + b_out : [64,1024]@[1024,512]. h_T is in h buf 0 (T even).
// 128 WGs: 4 row-tiles x 32 col-tiles of 16x16; 4 waves K-split 256 each.
__global__ __launch_bounds__(256) void lstm_out(
    const f16* __restrict__ hbuf, const f16* __restrict__ WoT,
    const float* __restrict__ bout, float* __restrict__ out) {
  const int wgid = blockIdx.x;
  const int rowT = wgid >> 5;   // 0..3
  const int colT = wgid & 31;   // 0..31
  const int tid  = threadIdx.x;
  const int wave = tid >> 6;
  const int lane = tid & 63;
  const int r16  = lane & 15;
  const int ksel = (lane >> 4) * 8;

  const int g = rowT >> 1;
  const f16* hrow = hbuf + (long)g * 2 * 32 * H_            // group base (buf 0)
                  + (long)((rowT & 1) * 16 + r16) * H_;
  const f16* wrow = WoT + (long)(colT * 16 + r16) * H_;

  f32x4 acc = {};
  #pragma unroll
  for (int f = 0; f < 8; ++f) {
    f16x8 a  = *(const f16x8*)(hrow + 256 * wave + 32 * f + ksel);
    f16x8 bf = *(const f16x8*)(wrow + 256 * wave + 32 * f + ksel);
    acc = __builtin_amdgcn_mfma_f32_16x16x32_f16(a, bf, acc, 0, 0, 0);
  }

  __shared__ float red[4][16][20];
  #pragma unroll
  for (int r = 0; r < 4; ++r)
    red[wave][(lane >> 4) * 4 + r][lane & 15] = acc[r];
  __syncthreads();

  const int row = tid >> 4;   // 0..15
  const int col = tid & 15;
  float s = bout[colT * 16 + col];
  #pragma unroll
  for (int w = 0; w < 4; ++w) s += red[w][row][col];
  out[(long)(rowT * 16 + row) * OUT_ + colT * 16 + col] = s;
}

extern "C" void kernel_launch(void* const* d_in, const int* in_sizes, int n_in,
                              void* d_out, int out_size, void* d_ws, size_t ws_size,
                              hipStream_t stream) {
  const float* x    = (const float*)d_in[0];
  const float* W    = (const float*)d_in[1];
  const float* b    = (const float*)d_in[2];
  const float* Wout = (const float*)d_in[3];
  const float* bout = (const float*)d_in[4];
  float* out = (float*)d_out;

  if (ws_size < WS_NEED) return;  // avoid corrupting memory if ws too small

  char* wsb = (char*)d_ws;
  f16* x16  = (f16*)(wsb + X16_OFF);
  f16* WoT  = (f16*)(wsb + WOT_OFF);
  f16* hbuf = (f16*)(wsb + H_OFF);
  unsigned int* flags = (unsigned int*)(wsb + FLG_OFF);

  // zero h double-buffers (h0 = 0) and barrier flags
  hipMemsetAsync(wsb + H_OFF, 0, ZERO_BYTES, stream);

  lstm_prepass<<<1024, 256, 0, stream>>>(x, Wout, x16, WoT);

  // 256 WGs, >=2 fit per CU -> all co-resident.
  lstm_main<<<256, 256, 0, stream>>>(W, b, x16, hbuf, flags);

  lstm_out<<<128, 256, 0, stream>>>(hbuf, WoT, bout, out);
}